// Round 10
// baseline (4515.126 us; speedup 1.0000x reference)
//
#include <hip/hip_runtime.h>

// DCRNN decoder R9 (resubmit after infra timeout): diffusion GEMM re-tiled
// 256^2 -> 128^2 (BK=64, 4 waves, LDS 64KB) keeping the 8-phase counted-vmcnt
// schedule => 2 blocks/CU so cross-block wave overlap fills the MFMA pipe
// during read/stage windows.
// Stage slots: A1->P0/P1 (just-in-time), B0'->P2/P3, A0'->P4/P5, B1'->P6/P7;
// boundary waits VMCNT(4) (12 outstanding, drain 8). Other kernels unchanged.
// Layouts:
//  H0/H1:  [b][kp(1024)][o(64)] f32
//  XT:     [row][kp] bf16 (B-operand, K-contiguous)
//  AG:     [j][m(1024)][slot] bf16; L0 slot=b*96+l; L1 slot=b*128+l
//  RUb:    [(m*64+b)][128] bf16 gates

#define BB 64
#define TT 12
#define NN 1000

typedef __bf16 bf16x8 __attribute__((ext_vector_type(8)));
typedef float f32x4 __attribute__((ext_vector_type(4)));
typedef unsigned short u16x8 __attribute__((ext_vector_type(8)));

__device__ __forceinline__ unsigned short f2b(float f) {
  union { float f; unsigned u; } x; x.f = f;
  unsigned u = x.u;
  u += 0x7FFFu + ((u >> 16) & 1u);
  return (unsigned short)(u >> 16);
}
__device__ __forceinline__ float b2f(unsigned short s) {
  union { float f; unsigned u; } x; x.u = ((unsigned)s) << 16; return x.f;
}

__device__ __forceinline__ void gload16(const void* g, void* l) {
  __builtin_amdgcn_global_load_lds((const __attribute__((address_space(1))) void*)g,
                                   (__attribute__((address_space(3))) void*)l, 16, 0, 0);
}

#define FENCE asm volatile("" ::: "memory")
#define BAR { FENCE; __builtin_amdgcn_s_barrier(); FENCE; }
#define VMCNT(n) asm volatile("s_waitcnt vmcnt(" #n ")" ::: "memory")

// ---------------- setup kernels ----------------

__global__ void prep_s_k(const float* __restrict__ S, unsigned short* __restrict__ Sb) {
  long idx = (long)blockIdx.x * 256 + threadIdx.x;   // 4*1024*1024
  if (idx >= 4194304L) return;
  int j = (int)(idx >> 20);
  int r = (int)((idx >> 10) & 1023);
  int c = (int)(idx & 1023);
  float v = (r < NN && c < NN) ? S[((long)j * NN + r) * NN + c] : 0.f;
  Sb[idx] = f2b(v);
}

__global__ void prep_wt_k(const float* __restrict__ wA, const float* __restrict__ wB,
                          unsigned short* __restrict__ WT, int F, int Fpad) {
  int Kt = 4 * Fpad;
  int idx = blockIdx.x * 256 + threadIdx.x;
  if (idx >= 128 * Kt) return;
  int o = idx / Kt, kk = idx % Kt;
  int j = kk / Fpad, l = kk % Fpad;
  float v = 0.f;
  if (l < F) {
    if (o < 64) v = wA ? wA[((long)j * F + l) * 64 + o] : 0.f;
    else        v = wB ? wB[((long)j * F + l) * 64 + (o - 64)] : 0.f;
  }
  WT[idx] = f2b(v);
}

__global__ void init_h2_k(const float* __restrict__ ih, float* __restrict__ H0,
                          float* __restrict__ H1) {
  long idx = (long)blockIdx.x * 256 + threadIdx.x;   // 4,096,000
  if (idx >= 4096000L) return;
  int b = (int)(idx / 64000);
  int rem = (int)(idx % 64000);
  int n = rem >> 6, o = rem & 63;
  long dst = ((long)((b << 10) | n)) * 64 + o;
  H0[dst] = ih[idx];
  H1[dst] = ih[4096000L + idx];
}

__global__ void build_xallT_k(const float* __restrict__ inp, unsigned short* __restrict__ XT) {
  unsigned idx = blockIdx.x * 256 + threadIdx.x;     // 768*1024
  if (idx >= 786432u) return;
  int k = idx & 1023, row = idx >> 10;
  int t = row >> 6, b = row & 63;
  float v = (t < TT - 1 && k < NN) ? inp[((long)b * TT + t) * NN + k] : 0.f;
  XT[idx] = f2b(v);
}

__global__ void scatter_x_k(const unsigned short* __restrict__ XAG,
                            unsigned short* __restrict__ AG, int t) {
  unsigned idx = blockIdx.x * 256 + threadIdx.x;
  if (idx >= 262144u) return;
  int b = idx & 63, m = (idx >> 6) & 1023, j = idx >> 16;
  long base = ((long)((j << 10) | m)) * 6144 + b * 96;
  AG[base] = XAG[((long)((j << 10) | m)) * 768 + t * 64 + b];
  u16x8 z = {0, 0, 0, 0, 0, 0, 0, 0};
  *(u16x8*)(AG + base + 64) = z;
  *(u16x8*)(AG + base + 72) = z;
  *(u16x8*)(AG + base + 80) = z;
  *(u16x8*)(AG + base + 88) = z;
}

// ---------------- transpose builds ----------------
template <int RMUL>
__global__ void build_hT_k(const float* __restrict__ H, const unsigned short* __restrict__ RUb,
                           unsigned short* __restrict__ XT) {
  __shared__ float tile[128][65];
  int k0 = blockIdx.x * 128, b = blockIdx.y, tid = threadIdx.x;
  for (int q = 0; q < 32; ++q) {
    int kk = q * 4 + (tid >> 6), o = tid & 63;
    int k = k0 + kk;
    float v = 0.f;
    if (k < NN) {
      v = H[((long)((b << 10) | k)) * 64 + o];
      if (RMUL) v *= b2f(RUb[((long)(k * 64 + b)) * 128 + o]);
    }
    tile[kk][o] = v;
  }
  __syncthreads();
  for (int q = 0; q < 32; ++q) {
    int idx = q * 256 + tid;
    int o = idx >> 7, kk = idx & 127;
    XT[(((long)(b * 64 + o)) << 10) + k0 + kk] = f2b(tile[kk][o]);
  }
}

__global__ void build_h01T_k(const float* __restrict__ H0, const float* __restrict__ H1,
                             unsigned short* __restrict__ XT) {
  __shared__ float tile[128][65];
  int k0 = blockIdx.x * 128, b = blockIdx.y, tid = threadIdx.x;
  for (int src = 0; src < 2; ++src) {
    const float* H = src ? H1 : H0;
    if (src) __syncthreads();
    for (int q = 0; q < 32; ++q) {
      int kk = q * 4 + (tid >> 6), o = tid & 63;
      int k = k0 + kk;
      tile[kk][o] = (k < NN) ? H[((long)((b << 10) | k)) * 64 + o] : 0.f;
    }
    __syncthreads();
    for (int q = 0; q < 32; ++q) {
      int idx = q * 256 + tid;
      int o = idx >> 7, kk = idx & 127;
      XT[(((long)(b * 128 + src * 64 + o)) << 10) + k0 + kk] = f2b(tile[kk][o]);
    }
  }
}

// ---------------- 128^2 8-phase diffusion GEMM ----------------
// C = A[1024][1024] (z-batched) * BT[*][1024]^T, K=1024. BM=BN=128, BK=64,
// 4 waves (2Mx2N), per-wave 64x64 out, 2 K-tiles/iteration, LDS 64KB
// (2 dbuf x (A 16K + B 16K)) => 2 blocks/CU.
// Swizzle: byte ^= (row&7)<<4 on gload-source and ds_read (LDS dest linear).

// stage one half-tile (64 rows x 128B) of a 128-row tile slab; 2 loads/thread
__device__ __forceinline__ void stage128(const char* Gp, char* L, int s, int tid) {
#pragma unroll
  for (int q = 0; q < 2; ++q) {
    int row = s * 64 + q * 32 + (tid >> 3);
    int cb = ((tid & 7) * 16) ^ ((row & 7) << 4);
    gload16(Gp + (long)row * 2048 + cb, L + row * 128 + (tid & 7) * 16);
  }
}

// read 2x2 fragment block (2 row-groups x 2 ks) from a 128-row LDS tile
__device__ __forceinline__ void rd2(const char* L, bf16x8 (&f)[2][2], int rowbase, int l) {
  int lr = l & 15, g = (l >> 4) * 16;
#pragma unroll
  for (int i = 0; i < 2; ++i) {
    int row = rowbase + i * 16 + lr;
#pragma unroll
    for (int ks = 0; ks < 2; ++ks)
      f[i][ks] = *(const bf16x8*)(L + row * 128 + ((ks * 64 + g) ^ ((row & 7) << 4)));
  }
}

template <int MI0, int NI0>
__device__ __forceinline__ void mfma8(f32x4 (&acc)[4][4], bf16x8 (&a2)[2][2],
                                      bf16x8 (&b2)[2][2]) {
  asm volatile("s_waitcnt lgkmcnt(0)" ::: "memory");
  __builtin_amdgcn_sched_barrier(0);
  __builtin_amdgcn_s_setprio(1);
#pragma unroll
  for (int ks = 0; ks < 2; ++ks)
#pragma unroll
    for (int mi = 0; mi < 2; ++mi)
#pragma unroll
      for (int ni = 0; ni < 2; ++ni)
        acc[MI0 + mi][NI0 + ni] = __builtin_amdgcn_mfma_f32_16x16x32_bf16(
            a2[mi][ks], b2[ni][ks], acc[MI0 + mi][NI0 + ni], 0, 0, 0);
  __builtin_amdgcn_s_setprio(0);
}

__global__ __launch_bounds__(256, 2)
void gemm128_k(const unsigned short* __restrict__ A, long azstr,
               const unsigned short* __restrict__ BT,
               void* __restrict__ Cv, long czstr, int ldc, int cstr, int coff) {
  alignas(16) __shared__ char lds[65536];
  char* A0 = lds;
  char* B0 = lds + 16384;
  char* A1 = lds + 32768;
  char* B1 = lds + 49152;

  // XCD-aware bijective swizzle (all grids have nwg % 8 == 0)
  unsigned nwx = gridDim.x, nwy = gridDim.y;
  unsigned lid = blockIdx.x + nwx * (blockIdx.y + nwy * blockIdx.z);
  unsigned cpx = (nwx * nwy * gridDim.z) >> 3;
  unsigned swz = (lid & 7u) * cpx + (lid >> 3);
  unsigned bx = swz % nwx;
  unsigned tmp = swz / nwx;
  unsigned by = tmp % nwy, bz = tmp / nwy;

  const int tid = threadIdx.x;
  const int l = tid & 63;
  const int w = tid >> 6;
  const int wr = (w >> 1) * 64;      // wave M-offset
  const int wc = (w & 1) * 64;       // wave N-offset
  const long m0 = (long)bx * 128;
  const long n0 = (long)by * 128;

  const char* Ag = (const char*)A + (long)bz * azstr * 2 + m0 * 2048;
  const char* Bg = (const char*)BT + n0 * 2048;

  f32x4 acc[4][4];
#pragma unroll
  for (int i = 0; i < 4; ++i)
#pragma unroll
    for (int j = 0; j < 4; ++j)
      acc[i][j] = (f32x4){0.f, 0.f, 0.f, 0.f};
  bf16x8 aLo[2][2], aHi[2][2], bLo[2][2], bHi[2][2];

  // prologue: buf0 <- kt0 (A0,B0 full), buf1 <- kt1 (B1 full; A1 staged in-loop)
  stage128(Bg, B0, 0, tid);
  stage128(Bg, B0, 1, tid);
  stage128(Ag, A0, 0, tid);
  stage128(Ag, A0, 1, tid);
  stage128(Bg + 128, B1, 0, tid);
  stage128(Bg + 128, B1, 1, tid);
  VMCNT(4);
  BAR;

  for (int it = 0; it < 8; ++it) {
    const bool L7 = (it == 7);
    const int k0b = it * 256;        // kt0 bytes; +128 kt1; +256 kt0+2; +384 kt1+2
    // P0: q(lo,lo) of buf0; stage A1.h0 <- kt1 (just-in-time, unconditional)
    VMCNT(4);
    rd2(A0, aLo, wr, l);
    rd2(B0, bLo, wc, l);
    stage128(Ag + k0b + 128, A1, 0, tid);
    BAR; mfma8<0, 0>(acc, aLo, bLo); BAR;
    // P1: q(lo,hi); stage A1.h1 (unconditional)
    rd2(B0, bHi, wc + 32, l);
    stage128(Ag + k0b + 128, A1, 1, tid);
    BAR; mfma8<0, 2>(acc, aLo, bHi); BAR;
    // P2: q(hi,hi); stage B0.h0 <- kt0+2
    rd2(A0, aHi, wr + 32, l);
    if (!L7) stage128(Bg + k0b + 256, B0, 0, tid);
    BAR; mfma8<2, 2>(acc, aHi, bHi); BAR;
    // P3: q(hi,lo); stage B0.h1
    if (!L7) stage128(Bg + k0b + 256, B0, 1, tid);
    BAR; mfma8<2, 0>(acc, aHi, bLo); BAR;
    // P4: q(lo,lo) of buf1; stage A0.h0 <- kt0+2
    if (L7) { VMCNT(0); } else { VMCNT(4); }
    rd2(A1, aLo, wr, l);
    rd2(B1, bLo, wc, l);
    if (!L7) stage128(Ag + k0b + 256, A0, 0, tid);
    BAR; mfma8<0, 0>(acc, aLo, bLo); BAR;
    // P5: q(lo,hi); stage A0.h1
    rd2(B1, bHi, wc + 32, l);
    if (!L7) stage128(Ag + k0b + 256, A0, 1, tid);
    BAR; mfma8<0, 2>(acc, aLo, bHi); BAR;
    // P6: q(hi,hi); stage B1.h0 <- kt1+2
    rd2(A1, aHi, wr + 32, l);
    if (!L7) stage128(Bg + k0b + 384, B1, 0, tid);
    BAR; mfma8<2, 2>(acc, aHi, bHi); BAR;
    // P7: q(hi,lo); stage B1.h1
    if (!L7) stage128(Bg + k0b + 384, B1, 1, tid);
    BAR; mfma8<2, 0>(acc, aHi, bLo); BAR;
  }

  // epilogue: bf16 store with column remap
  unsigned short* C = (unsigned short*)Cv + (long)bz * czstr;
  const int rb = (l >> 4) * 4, cl = l & 15;
#pragma unroll
  for (int mi = 0; mi < 4; ++mi) {
    long r = m0 + wr + mi * 16 + rb;
#pragma unroll
    for (int ni = 0; ni < 4; ++ni) {
      int c = (int)(n0 + wc + ni * 16 + cl);
      long cb = (long)(c >> 6) * cstr + coff + (c & 63);
#pragma unroll
      for (int jj = 0; jj < 4; ++jj)
        C[(r + jj) * (long)ldc + cb] = f2b(acc[mi][ni][jj]);
    }
  }
}

// ---------------- small MFMA GEMM (K=384/512) ----------------
// EPI 1: RUb[r*128+c] = bf16(sigmoid(acc + bias)) (p0 = b_r, p1v = b_u)
// EPI 4: c<64: H[((r&63)<<10 | r>>6)*64+c] = u*h + (1-u)*tanh(acc+p0[c])
template <int EPI>
__global__ __launch_bounds__(256)
void gemm_k(const unsigned short* __restrict__ A, long azstr, int lda, int acs, long ajstr,
            const unsigned short* __restrict__ BT, int ldb, int ksteps,
            void* __restrict__ Cv, long czstr, int ldc, int cstr, int coff,
            const float* __restrict__ p0, const void* __restrict__ p1v) {
  __shared__ unsigned short As[4096];
  __shared__ unsigned short Bs[4096];
  unsigned bx = blockIdx.x, by = blockIdx.y, bz = blockIdx.z;

  const int tid = threadIdx.x;
  const int lane = tid & 63;
  const int w = tid >> 6;
  const int wr = (w >> 1) * 64, wc = (w & 1) * 64;
  const long m0 = (long)bx * 128;
  const long n0 = (long)by * 128;
  A += (long)bz * azstr;

  const int rl = lane & 15;
  const int kb = (lane >> 4) * 8;
  const int s_r = tid >> 2;
  const int s_k = (tid & 3) * 8;

  f32x4 acc[4][4];
  for (int i = 0; i < 4; ++i)
    for (int j = 0; j < 4; ++j)
      acc[i][j] = (f32x4){0.f, 0.f, 0.f, 0.f};

  int jc = 0, lc = 0;
  for (int kt = 0; kt < ksteps; ++kt) {
    const unsigned short* Astep = A + (long)jc * ajstr + (long)lc * 32;
    const unsigned short* Bstep = BT + (long)kt * 32;
    gload16(Astep + (m0 + s_r) * (long)lda + s_k,       &As[tid * 8]);
    gload16(Astep + (m0 + 64 + s_r) * (long)lda + s_k,  &As[2048 + tid * 8]);
    gload16(Bstep + (n0 + s_r) * (long)ldb + s_k,       &Bs[tid * 8]);
    gload16(Bstep + (n0 + 64 + s_r) * (long)ldb + s_k,  &Bs[2048 + tid * 8]);
    __syncthreads();
    bf16x8 af[4], bg[4];
#pragma unroll
    for (int i = 0; i < 4; ++i) {
      af[i] = *(const bf16x8*)((const void*)&As[(wr + i * 16 + rl) * 32 + kb]);
      bg[i] = *(const bf16x8*)((const void*)&Bs[(wc + i * 16 + rl) * 32 + kb]);
    }
#pragma unroll
    for (int mi = 0; mi < 4; ++mi)
#pragma unroll
      for (int ni = 0; ni < 4; ++ni)
        acc[mi][ni] = __builtin_amdgcn_mfma_f32_16x16x32_bf16(af[mi], bg[ni], acc[mi][ni], 0, 0, 0);
    __syncthreads();
    if (++lc == acs) { lc = 0; ++jc; }
  }

  const int rb = (lane >> 4) * 4;
  const int cl = lane & 15;
  if constexpr (EPI == 1) {
    unsigned short* RUo = (unsigned short*)Cv;
    const float* bu = (const float*)p1v;
#pragma unroll
    for (int mi = 0; mi < 4; ++mi) {
      long r = m0 + wr + mi * 16 + rb;
#pragma unroll
      for (int ni = 0; ni < 4; ++ni) {
        int c = (int)(n0 + wc + ni * 16 + cl);
        float bias = (c < 64) ? p0[c] : bu[c - 64];
#pragma unroll
        for (int jj = 0; jj < 4; ++jj) {
          float v = acc[mi][ni][jj] + bias;
          RUo[(r + jj) * 128 + c] = f2b(1.f / (1.f + __expf(-v)));
        }
      }
    }
  } else {  // EPI == 4
    float* H = (float*)Cv;
    const unsigned short* RUb = (const unsigned short*)p1v;
#pragma unroll
    for (int mi = 0; mi < 4; ++mi) {
      long r = m0 + wr + mi * 16 + rb;
#pragma unroll
      for (int ni = 0; ni < 4; ++ni) {
        int c = (int)(n0 + wc + ni * 16 + cl);
        if (c < 64) {
#pragma unroll
          for (int jj = 0; jj < 4; ++jj) {
            long rr = r + jj;
            float cv = tanhf(acc[mi][ni][jj] + p0[c]);
            float u = b2f(RUb[rr * 128 + 64 + c]);
            long ha = ((((rr & 63)) << 10) + (rr >> 6)) * 64 + c;
            H[ha] = u * H[ha] + (1.f - u) * cv;
          }
        }
      }
    }
  }
}

// ---------------- projection ----------------
__global__ void proj_k(const float* __restrict__ H1, const float* __restrict__ pw,
                       const float* __restrict__ pb, float* __restrict__ out, int t) {
  __shared__ float tile[250][65];
  __shared__ float pws[64];
  int b = blockIdx.y, n0 = blockIdx.x * 250, tid = threadIdx.x;
  if (tid < 64) pws[tid] = pw[tid];
  for (int flat = tid; flat < 16000; flat += 256) {
    int nl = flat >> 6, o = flat & 63;
    tile[nl][o] = H1[((long)((b << 10) | (n0 + nl))) * 64 + o];
  }
  __syncthreads();
  if (tid < 250) {
    float s = pb[0];
#pragma unroll
    for (int o = 0; o < 64; ++o) s += tile[tid][o] * pws[o];
    out[((long)b * (TT - 1) + t) * NN + n0 + tid] = s;
  }
}

// ---------------- launcher ----------------
extern "C" void kernel_launch(void* const* d_in, const int* in_sizes, int n_in,
                              void* d_out, int out_size, void* d_ws, size_t ws_size,
                              hipStream_t stream) {
  const float* inp = (const float*)d_in[0];
  const float* ih  = (const float*)d_in[1];
  const float* sup = (const float*)d_in[2];
  const float* w0r = (const float*)d_in[4];
  const float* b0r = (const float*)d_in[5];
  const float* w0u = (const float*)d_in[6];
  const float* b0u = (const float*)d_in[7];
  const float* w0c = (const float*)d_in[8];
  const float* b0c = (const float*)d_in[9];
  const float* w1r = (const float*)d_in[10];
  const float* b1r = (const float*)d_in[11];
  const float* w1u = (const float*)d_in[12];
  const float* b1u = (const float*)d_in[13];
  const float* w1c = (const float*)d_in[14];
  const float* b1c = (const float*)d_in[15];
  const float* pw  = (const float*)d_in[16];
  const float* pb  = (const float*)d_in[17];
  float* out = (float*)d_out;

  char* ws = (char*)d_ws;
  unsigned short* Sb   = (unsigned short*)(ws + 0);            //  8,388,608
  unsigned short* AG   = (unsigned short*)(ws + 8388608);      // 67,108,864
  unsigned short* XT   = (unsigned short*)(ws + 75497472);     // 16,777,216
  unsigned short* XAG  = (unsigned short*)(ws + 92274688);     //  6,291,456
  unsigned short* RUb  = (unsigned short*)(ws + 98566144);     // 16,384,000
  float* H0            = (float*)(ws + 114950144);             // 16,777,216
  float* H1            = (float*)(ws + 131727360);             // 16,777,216
  unsigned short* Wru0 = (unsigned short*)(ws + 148504576);    //     98,304
  unsigned short* Wc0  = (unsigned short*)(ws + 148602880);    //     98,304
  unsigned short* Wru1 = (unsigned short*)(ws + 148701184);    //    131,072
  unsigned short* Wc1  = (unsigned short*)(ws + 148832256);    //    131,072

  // ---- setup ----
  prep_s_k<<<16384, 256, 0, stream>>>(sup, Sb);
  prep_wt_k<<<192, 256, 0, stream>>>(w0r, w0u, Wru0, 65, 96);
  prep_wt_k<<<192, 256, 0, stream>>>(w0c, nullptr, Wc0, 65, 96);
  prep_wt_k<<<256, 256, 0, stream>>>(w1r, w1u, Wru1, 128, 128);
  prep_wt_k<<<256, 256, 0, stream>>>(w1c, nullptr, Wc1, 128, 128);
  init_h2_k<<<16000, 256, 0, stream>>>(ih, H0, H1);
  build_xallT_k<<<3072, 256, 0, stream>>>(inp, XT);
  // XAG[j][m][(t,b)] = S_j @ x_all
  gemm128_k<<<dim3(8, 6, 4), 256, 0, stream>>>(Sb, 1048576L, XT, XAG, 786432L, 768, 64, 0);

  for (int t = 0; t < TT - 1; ++t) {
    // ---- layer 0 ----
    scatter_x_k<<<1024, 256, 0, stream>>>(XAG, AG, t);
    build_hT_k<0><<<dim3(8, 64), 256, 0, stream>>>(H0, nullptr, XT);
    gemm128_k<<<dim3(8, 48, 4), 256, 0, stream>>>(Sb, 1048576L, XT, AG, 6291456L, 6144, 96, 1);
    gemm_k<1><<<dim3(500, 1, 1), 256, 0, stream>>>(
        AG, 0, 96, 3, 6291456L, Wru0, 384, 12, RUb, 0, 0, 0, 0, b0r, b0u);
    build_hT_k<1><<<dim3(8, 64), 256, 0, stream>>>(H0, RUb, XT);
    gemm128_k<<<dim3(8, 48, 4), 256, 0, stream>>>(Sb, 1048576L, XT, AG, 6291456L, 6144, 96, 1);
    gemm_k<4><<<dim3(500, 1, 1), 256, 0, stream>>>(
        AG, 0, 96, 3, 6291456L, Wc0, 384, 12, H0, 0, 0, 0, 0, b0c, RUb);
    // ---- layer 1 ----
    build_h01T_k<<<dim3(8, 64), 256, 0, stream>>>(H0, H1, XT);
    gemm128_k<<<dim3(8, 64, 4), 256, 0, stream>>>(Sb, 1048576L, XT, AG, 8388608L, 8192, 64, 0);
    gemm_k<1><<<dim3(500, 1, 1), 256, 0, stream>>>(
        AG, 0, 128, 4, 8388608L, Wru1, 512, 16, RUb, 0, 0, 0, 0, b1r, b1u);
    build_hT_k<1><<<dim3(8, 64), 256, 0, stream>>>(H1, RUb, XT);
    gemm128_k<<<dim3(8, 32, 4), 256, 0, stream>>>(Sb, 1048576L, XT, AG, 8388608L, 8192, 128, 64);
    gemm_k<4><<<dim3(500, 1, 1), 256, 0, stream>>>(
        AG, 0, 128, 4, 8388608L, Wc1, 512, 16, H1, 0, 0, 0, 0, b1c, RUb);
    // ---- output projection ----
    proj_k<<<dim3(4, 64), 256, 0, stream>>>(H1, pw, pb, out, t);
  }
}